// Round 1
// baseline (358.126 us; speedup 1.0000x reference)
//
#include <hip/hip_runtime.h>
#include <math.h>

#define N_REFLNS 2000000
#define N_IMAGES 8192
#define N_RAC    1000000
#define MC       8
#define D_META   16
#define HIDDEN   32
#define LOG_2PI  1.8378770664093453f

// Workspace layout (bytes):
//   [0, 32768)          img_sum   (8192 f32)
//   [32768, 65536)      img_cnt   (8192 f32)
//   [65536, 65540)      kl_sum    (1 f32)
//   [65664, 65664+32e6) zT        (N_RAC x MC f32, transposed z for 32B gathers)

__device__ __forceinline__ float softplus_f(float x) {
    // log1p(exp(x)) stable: max(x,0) + log1p(exp(-|x|))
    return fmaxf(x, 0.0f) + log1pf(expf(-fabsf(x)));
}

__global__ __launch_bounds__(256) void k_z_kl(
    const float* __restrict__ q_loc,
    const float* __restrict__ q_log_scale,
    const float* __restrict__ eps,
    float* __restrict__ zT,          // may be null (fallback)
    float* __restrict__ kl_sum)
{
    int r = blockIdx.x * 256 + threadIdx.x;
    float kl = 0.0f;
    if (r < N_RAC) {
        float ql  = q_loc[r];
        float qls = q_log_scale[r];
        float qs  = expf(qls);
        kl = 0.5f * (qs * qs + ql * ql - 1.0f) - qls;
        if (zT) {
            float4 z0, z1;
            z0.x = ql + qs * eps[0 * N_RAC + r];
            z0.y = ql + qs * eps[1 * N_RAC + r];
            z0.z = ql + qs * eps[2 * N_RAC + r];
            z0.w = ql + qs * eps[3 * N_RAC + r];
            z1.x = ql + qs * eps[4 * N_RAC + r];
            z1.y = ql + qs * eps[5 * N_RAC + r];
            z1.z = ql + qs * eps[6 * N_RAC + r];
            z1.w = ql + qs * eps[7 * N_RAC + r];
            float4* dst = (float4*)(zT + (size_t)r * MC);
            dst[0] = z0;
            dst[1] = z1;
        }
    }
    __shared__ float sred[256];
    sred[threadIdx.x] = kl;
    __syncthreads();
    #pragma unroll
    for (int s = 128; s > 0; s >>= 1) {
        if (threadIdx.x < s) sred[threadIdx.x] += sred[threadIdx.x + s];
        __syncthreads();
    }
    if (threadIdx.x == 0) atomicAdd(kl_sum, sred[0]);
}

template <bool HAS_Z>
__global__ __launch_bounds__(256) void k_main(
    const float* __restrict__ metadata,
    const float* __restrict__ W1, const float* __restrict__ b1,
    const float* __restrict__ W2, const float* __restrict__ b2,
    const float* __restrict__ iobs, const float* __restrict__ sigiobs,
    const int* __restrict__ image_id, const int* __restrict__ miller_id,
    const float* __restrict__ zT,
    const float* __restrict__ q_loc, const float* __restrict__ q_log_scale,
    const float* __restrict__ eps,
    float* __restrict__ out_ipred,
    float* __restrict__ img_sum, float* __restrict__ img_cnt)
{
    __shared__ float sW1[D_META * HIDDEN];
    __shared__ float sb1[HIDDEN];
    __shared__ float sW2[HIDDEN * MC];
    __shared__ float sb2[MC];
    __shared__ float s_ll[256];
    __shared__ float s_ct[256];
    __shared__ int   s_id[256];

    int tid = threadIdx.x;
    for (int i = tid; i < D_META * HIDDEN; i += 256) sW1[i] = W1[i];
    if (tid < HIDDEN) sb1[tid] = b1[tid];
    for (int i = tid; i < HIDDEN * MC; i += 256) sW2[i] = W2[i];
    if (tid < MC) sb2[tid] = b2[tid];
    __syncthreads();

    int n = blockIdx.x * 256 + tid;
    bool valid = (n < N_REFLNS);
    float ll_sum = 0.0f;
    int img = -1;

    if (valid) {
        const float4* mrow = (const float4*)(metadata + (size_t)n * D_META);
        float4 m0 = mrow[0], m1 = mrow[1], m2 = mrow[2], m3 = mrow[3];
        float meta[D_META] = {m0.x, m0.y, m0.z, m0.w,
                              m1.x, m1.y, m1.z, m1.w,
                              m2.x, m2.y, m2.z, m2.w,
                              m3.x, m3.y, m3.z, m3.w};
        float acc[MC];
        #pragma unroll
        for (int s = 0; s < MC; s++) acc[s] = sb2[s];
        #pragma unroll
        for (int j = 0; j < HIDDEN; j++) {
            float hj = sb1[j];
            #pragma unroll
            for (int d = 0; d < D_META; d++) hj = fmaf(meta[d], sW1[d * HIDDEN + j], hj);
            hj = fmaxf(hj, 0.0f);
            #pragma unroll
            for (int s = 0; s < MC; s++) acc[s] = fmaf(hj, sW2[j * MC + s], acc[s]);
        }

        int m = miller_id[n];
        float f[MC];
        if (HAS_Z) {
            const float4* zp = (const float4*)(zT + (size_t)m * MC);
            float4 z0 = zp[0], z1 = zp[1];
            f[0] = z0.x; f[1] = z0.y; f[2] = z0.z; f[3] = z0.w;
            f[4] = z1.x; f[5] = z1.y; f[6] = z1.z; f[7] = z1.w;
        } else {
            float ql = q_loc[m];
            float qs = expf(q_log_scale[m]);
            #pragma unroll
            for (int s = 0; s < MC; s++) f[s] = ql + qs * eps[(size_t)s * N_RAC + m];
        }

        float io = iobs[n];
        float sg = sigiobs[n];
        float inv_sg = 1.0f / sg;
        float sum_ip = 0.0f, sum_r2 = 0.0f;
        #pragma unroll
        for (int s = 0; s < MC; s++) {
            float sc = softplus_f(acc[s]);
            float ip = f[s] * f[s] * sc;
            sum_ip += ip;
            float r = (ip - io) * inv_sg;
            sum_r2 = fmaf(r, r, sum_r2);
        }
        out_ipred[n] = sum_ip * (1.0f / MC);
        ll_sum = -0.5f * sum_r2 - (float)MC * (logf(sg) + 0.5f * LOG_2PI);
        img = image_id[n];
    }

    // Segmented inclusive scan over sorted image ids (Hillis-Steele).
    s_ll[tid] = ll_sum;
    s_ct[tid] = valid ? 1.0f : 0.0f;
    s_id[tid] = img;
    __syncthreads();
    #pragma unroll
    for (int d = 1; d < 256; d <<= 1) {
        float a = 0.0f, c = 0.0f;
        if (tid >= d && s_id[tid] == s_id[tid - d]) {
            a = s_ll[tid - d];
            c = s_ct[tid - d];
        }
        __syncthreads();
        s_ll[tid] += a;
        s_ct[tid] += c;
        __syncthreads();
    }
    if (valid) {
        bool tail = (tid == 255) || (s_id[tid + 1] != img);
        if (tail) {
            atomicAdd(&img_sum[img], s_ll[tid]);
            atomicAdd(&img_cnt[img], s_ct[tid]);
        }
    }
}

__global__ __launch_bounds__(256) void k_final(
    const float* __restrict__ img_sum,
    const float* __restrict__ img_cnt,
    const float* __restrict__ kl_sum,
    float* __restrict__ out)
{
    __shared__ float sred[256];
    float acc = 0.0f;
    for (int i = threadIdx.x; i < N_IMAGES; i += 256) {
        acc += img_sum[i] / fmaxf(img_cnt[i], 1.0f);
    }
    sred[threadIdx.x] = acc;
    __syncthreads();
    #pragma unroll
    for (int s = 128; s > 0; s >>= 1) {
        if (threadIdx.x < s) sred[threadIdx.x] += sred[threadIdx.x + s];
        __syncthreads();
    }
    if (threadIdx.x == 0) {
        float mean_ll = sred[0] / ((float)MC * (float)N_IMAGES);
        out[N_REFLNS]     = -mean_ll;
        out[N_REFLNS + 1] = kl_sum[0] * (1.0f / (float)N_RAC);
    }
}

extern "C" void kernel_launch(void* const* d_in, const int* in_sizes, int n_in,
                              void* d_out, int out_size, void* d_ws, size_t ws_size,
                              hipStream_t stream) {
    const float* q_loc       = (const float*)d_in[0];
    const float* q_log_scale = (const float*)d_in[1];
    const float* eps         = (const float*)d_in[2];
    const float* metadata    = (const float*)d_in[3];
    const float* W1          = (const float*)d_in[4];
    const float* b1          = (const float*)d_in[5];
    const float* W2          = (const float*)d_in[6];
    const float* b2          = (const float*)d_in[7];
    const float* iobs        = (const float*)d_in[8];
    const float* sigiobs     = (const float*)d_in[9];
    const int*   image_id    = (const int*)d_in[10];
    const int*   miller_id   = (const int*)d_in[11];
    float* out = (float*)d_out;

    char* ws = (char*)d_ws;
    float* img_sum = (float*)ws;                 // 8192
    float* img_cnt = img_sum + N_IMAGES;         // 8192
    float* kl_sum  = img_cnt + N_IMAGES;         // 1
    const size_t z_off = 65664;
    bool has_z = (ws_size >= z_off + (size_t)N_RAC * MC * sizeof(float));
    float* zT = has_z ? (float*)(ws + z_off) : nullptr;

    hipMemsetAsync(d_ws, 0, (2 * N_IMAGES + 1) * sizeof(float), stream);

    k_z_kl<<<(N_RAC + 255) / 256, 256, 0, stream>>>(q_loc, q_log_scale, eps, zT, kl_sum);

    if (has_z) {
        k_main<true><<<(N_REFLNS + 255) / 256, 256, 0, stream>>>(
            metadata, W1, b1, W2, b2, iobs, sigiobs, image_id, miller_id,
            zT, q_loc, q_log_scale, eps, out, img_sum, img_cnt);
    } else {
        k_main<false><<<(N_REFLNS + 255) / 256, 256, 0, stream>>>(
            metadata, W1, b1, W2, b2, iobs, sigiobs, image_id, miller_id,
            nullptr, q_loc, q_log_scale, eps, out, img_sum, img_cnt);
    }

    k_final<<<1, 256, 0, stream>>>(img_sum, img_cnt, kl_sum, out);
}

// Round 2
// 351.140 us; speedup vs baseline: 1.0199x; 1.0199x over previous
//
#include <hip/hip_runtime.h>
#include <math.h>

#define N_REFLNS 2000000
#define N_IMAGES 8192
#define N_RAC    1000000
#define MC       8
#define D_META   16
#define HIDDEN   32
#define LOG_2PI  1.8378770664093453f

// Workspace layout (bytes):
//   [0, 32768)          img_sum   (8192 f32)
//   [32768, 65536)      img_cnt   (8192 f32)
//   [65536, 65540)      kl_sum    (1 f32)
//   [65664, 65664+32e6) zT        (N_RAC x MC f32, transposed z for 32B gathers)

__device__ __forceinline__ float softplus_f(float x) {
    return fmaxf(x, 0.0f) + log1pf(expf(-fabsf(x)));
}

// ---------------- Kernel A: zT + KL, 4 RAC entries per thread ----------------
__global__ __launch_bounds__(256) void k_z_kl(
    const float* __restrict__ q_loc,
    const float* __restrict__ q_log_scale,
    const float* __restrict__ eps,
    float* __restrict__ zT,          // may be null (fallback)
    float* __restrict__ kl_sum)
{
    int t = blockIdx.x * 256 + threadIdx.x;
    int r0 = t * 4;
    float kl = 0.0f;
    if (r0 < N_RAC) {
        float4 ql  = *(const float4*)(q_loc + r0);
        float4 qls = *(const float4*)(q_log_scale + r0);
        float4 qs;
        qs.x = expf(qls.x); qs.y = expf(qls.y);
        qs.z = expf(qls.z); qs.w = expf(qls.w);
        kl = 0.5f * (qs.x * qs.x + ql.x * ql.x - 1.0f) - qls.x
           + 0.5f * (qs.y * qs.y + ql.y * ql.y - 1.0f) - qls.y
           + 0.5f * (qs.z * qs.z + ql.z * ql.z - 1.0f) - qls.z
           + 0.5f * (qs.w * qs.w + ql.w * ql.w - 1.0f) - qls.w;
        if (zT) {
            float zr[4][MC];
            #pragma unroll
            for (int s = 0; s < MC; s++) {
                float4 e = *(const float4*)(eps + (size_t)s * N_RAC + r0);
                zr[0][s] = ql.x + qs.x * e.x;
                zr[1][s] = ql.y + qs.y * e.y;
                zr[2][s] = ql.z + qs.z * e.z;
                zr[3][s] = ql.w + qs.w * e.w;
            }
            #pragma unroll
            for (int r = 0; r < 4; r++) {
                float4* dst = (float4*)(zT + (size_t)(r0 + r) * MC);
                dst[0] = make_float4(zr[r][0], zr[r][1], zr[r][2], zr[r][3]);
                dst[1] = make_float4(zr[r][4], zr[r][5], zr[r][6], zr[r][7]);
            }
        }
    }
    __shared__ float sred[256];
    sred[threadIdx.x] = kl;
    __syncthreads();
    #pragma unroll
    for (int s = 128; s > 0; s >>= 1) {
        if (threadIdx.x < s) sred[threadIdx.x] += sred[threadIdx.x + s];
        __syncthreads();
    }
    if (threadIdx.x == 0) atomicAdd(kl_sum, sred[0]);
}

// ---------------- Kernel B: MLP + likelihood, 4 reflections per thread -------
// LDS weight layout: per hidden unit j, a 28-float (112 B, 16B-aligned) block:
//   [0..15]  W1T row j  (W1[d][j], d=0..15)
//   [16..23] W2 row j   (W2[j][s], s=0..7)
//   [24]     b1[j]      [25..27] pad
template <bool HAS_Z>
__global__ __launch_bounds__(256) void k_main(
    const float* __restrict__ metadata,
    const float* __restrict__ W1, const float* __restrict__ b1,
    const float* __restrict__ W2, const float* __restrict__ b2,
    const float* __restrict__ iobs, const float* __restrict__ sigiobs,
    const int* __restrict__ image_id, const int* __restrict__ miller_id,
    const float* __restrict__ zT,
    const float* __restrict__ q_loc, const float* __restrict__ q_log_scale,
    const float* __restrict__ eps,
    float* __restrict__ out_ipred,
    float* __restrict__ img_sum, float* __restrict__ img_cnt)
{
    __shared__ float sW[HIDDEN * 28];
    __shared__ float sb2[MC];
    __shared__ int   s_id[512];
    __shared__ float s_ll[512];
    __shared__ float s_ct[512];

    int tid = threadIdx.x;
    for (int idx = tid; idx < HIDDEN * 28; idx += 256) {
        int j = idx / 28, k = idx % 28;
        float v = 0.0f;
        if (k < 16)       v = W1[k * HIDDEN + j];
        else if (k < 24)  v = W2[j * MC + (k - 16)];
        else if (k == 24) v = b1[j];
        sW[idx] = v;
    }
    if (tid < MC) sb2[tid] = b2[tid];
    __syncthreads();

    int n0 = (blockIdx.x * 256 + tid) * 4;
    bool valid = (n0 < N_REFLNS);   // N_REFLNS % 4 == 0: all-or-nothing per thread

    float ll[4] = {0.f, 0.f, 0.f, 0.f};
    int   id0 = -1, id1 = -1, id2 = -1, id3 = -1;
    float c = 0.0f;

    if (valid) {
        c = 1.0f;
        float m[4][D_META];
        #pragma unroll
        for (int r = 0; r < 4; r++) {
            const float4* mrow = (const float4*)(metadata + (size_t)(n0 + r) * D_META);
            #pragma unroll
            for (int q = 0; q < 4; q++) {
                float4 v = mrow[q];
                m[r][4 * q + 0] = v.x; m[r][4 * q + 1] = v.y;
                m[r][4 * q + 2] = v.z; m[r][4 * q + 3] = v.w;
            }
        }

        float acc[4][MC];
        #pragma unroll
        for (int r = 0; r < 4; r++)
            #pragma unroll
            for (int s = 0; s < MC; s++) acc[r][s] = sb2[s];

        #pragma unroll 4
        for (int j = 0; j < HIDDEN; j++) {
            const float* wr = &sW[j * 28];
            float4 wa = *(const float4*)(wr + 0);
            float4 wb = *(const float4*)(wr + 4);
            float4 wc = *(const float4*)(wr + 8);
            float4 wd = *(const float4*)(wr + 12);
            float w1v[D_META] = {wa.x, wa.y, wa.z, wa.w, wb.x, wb.y, wb.z, wb.w,
                                 wc.x, wc.y, wc.z, wc.w, wd.x, wd.y, wd.z, wd.w};
            float b1j = wr[24];
            float h[4];
            #pragma unroll
            for (int r = 0; r < 4; r++) {
                float hr = b1j;
                #pragma unroll
                for (int d = 0; d < D_META; d++) hr = fmaf(m[r][d], w1v[d], hr);
                h[r] = fmaxf(hr, 0.0f);
            }
            float4 w2a = *(const float4*)(wr + 16);
            float4 w2b = *(const float4*)(wr + 20);
            float w2v[MC] = {w2a.x, w2a.y, w2a.z, w2a.w, w2b.x, w2b.y, w2b.z, w2b.w};
            #pragma unroll
            for (int r = 0; r < 4; r++)
                #pragma unroll
                for (int s = 0; s < MC; s++) acc[r][s] = fmaf(h[r], w2v[s], acc[r][s]);
        }

        int4   mi = *(const int4*)(miller_id + n0);
        float4 io = *(const float4*)(iobs + n0);
        float4 sg = *(const float4*)(sigiobs + n0);
        int4   ii = *(const int4*)(image_id + n0);
        id0 = ii.x; id1 = ii.y; id2 = ii.z; id3 = ii.w;
        int   mids[4] = {mi.x, mi.y, mi.z, mi.w};
        float ios[4]  = {io.x, io.y, io.z, io.w};
        float sgs[4]  = {sg.x, sg.y, sg.z, sg.w};
        float out4[4];

        #pragma unroll
        for (int r = 0; r < 4; r++) {
            float f[MC];
            if (HAS_Z) {
                const float4* zp = (const float4*)(zT + (size_t)mids[r] * MC);
                float4 z0 = zp[0], z1 = zp[1];
                f[0] = z0.x; f[1] = z0.y; f[2] = z0.z; f[3] = z0.w;
                f[4] = z1.x; f[5] = z1.y; f[6] = z1.z; f[7] = z1.w;
            } else {
                float qlv = q_loc[mids[r]];
                float qsv = expf(q_log_scale[mids[r]]);
                #pragma unroll
                for (int s = 0; s < MC; s++) f[s] = qlv + qsv * eps[(size_t)s * N_RAC + mids[r]];
            }
            float inv_sg = 1.0f / sgs[r];
            float sum_ip = 0.0f, sum_r2 = 0.0f;
            #pragma unroll
            for (int s = 0; s < MC; s++) {
                float sc = softplus_f(acc[r][s]);
                float ip = f[s] * f[s] * sc;
                sum_ip += ip;
                float rr = (ip - ios[r]) * inv_sg;
                sum_r2 = fmaf(rr, rr, sum_r2);
            }
            out4[r] = sum_ip * (1.0f / MC);
            ll[r] = -0.5f * sum_r2 - (float)MC * (logf(sgs[r]) + 0.5f * LOG_2PI);
        }
        *(float4*)(out_ipred + n0) = make_float4(out4[0], out4[1], out4[2], out4[3]);
    }

    // ---- per-thread run compression (ids are globally sorted) ----
    bool e01 = (id0 == id1), e12 = (id1 == id2), e23 = (id2 == id3);
    float hll = ll[0], hct = c;
    if (e01) { hll += ll[1]; hct += c;
        if (e12) { hll += ll[2]; hct += c;
            if (e23) { hll += ll[3]; hct += c; } } }
    bool single = e01 && e12 && e23;
    int timg; float tll, tct;
    if (single) { timg = id0; tll = 0.0f; tct = 0.0f; }
    else {
        timg = id3; tll = ll[3]; tct = c;
        if (e23) { tll += ll[2]; tct += c;
            if (e12) { tll += ll[1]; tct += c; } }
        bool m1 = !e01 && !(e12 && e23);
        bool m2 = !(e01 && e12) && !e23;
        if (m1) { atomicAdd(&img_sum[id1], ll[1]); atomicAdd(&img_cnt[id1], c); }
        if (m2) { atomicAdd(&img_sum[id2], ll[2]); atomicAdd(&img_cnt[id2], c); }
    }

    s_id[2 * tid] = id0;  s_ll[2 * tid] = hll;  s_ct[2 * tid] = hct;
    s_id[2 * tid + 1] = timg; s_ll[2 * tid + 1] = tll; s_ct[2 * tid + 1] = tct;
    __syncthreads();

    // segmented Hillis-Steele over 512 slots (2 per thread)
    #pragma unroll
    for (int d = 1; d < 512; d <<= 1) {
        int s0 = tid, s1 = tid + 256;
        float a0 = 0.f, c0 = 0.f, a1 = 0.f, c1 = 0.f;
        if (s0 >= d && s_id[s0] == s_id[s0 - d]) { a0 = s_ll[s0 - d]; c0 = s_ct[s0 - d]; }
        if (s1 >= d && s_id[s1] == s_id[s1 - d]) { a1 = s_ll[s1 - d]; c1 = s_ct[s1 - d]; }
        __syncthreads();
        s_ll[s0] += a0; s_ct[s0] += c0;
        s_ll[s1] += a1; s_ct[s1] += c1;
        __syncthreads();
    }

    #pragma unroll
    for (int q = 0; q < 2; q++) {
        int s = tid + q * 256;
        bool end = (s == 511) || (s_id[s + 1] != s_id[s]);
        if (end && s_ct[s] > 0.0f) {
            atomicAdd(&img_sum[s_id[s]], s_ll[s]);
            atomicAdd(&img_cnt[s_id[s]], s_ct[s]);
        }
    }
}

// ---------------- Kernel C: finalize scalars ----------------
__global__ __launch_bounds__(256) void k_final(
    const float* __restrict__ img_sum,
    const float* __restrict__ img_cnt,
    const float* __restrict__ kl_sum,
    float* __restrict__ out)
{
    __shared__ float sred[256];
    float acc = 0.0f;
    for (int i = threadIdx.x; i < N_IMAGES; i += 256) {
        acc += img_sum[i] / fmaxf(img_cnt[i], 1.0f);
    }
    sred[threadIdx.x] = acc;
    __syncthreads();
    #pragma unroll
    for (int s = 128; s > 0; s >>= 1) {
        if (threadIdx.x < s) sred[threadIdx.x] += sred[threadIdx.x + s];
        __syncthreads();
    }
    if (threadIdx.x == 0) {
        float mean_ll = sred[0] / ((float)MC * (float)N_IMAGES);
        out[N_REFLNS]     = -mean_ll;
        out[N_REFLNS + 1] = kl_sum[0] * (1.0f / (float)N_RAC);
    }
}

extern "C" void kernel_launch(void* const* d_in, const int* in_sizes, int n_in,
                              void* d_out, int out_size, void* d_ws, size_t ws_size,
                              hipStream_t stream) {
    const float* q_loc       = (const float*)d_in[0];
    const float* q_log_scale = (const float*)d_in[1];
    const float* eps         = (const float*)d_in[2];
    const float* metadata    = (const float*)d_in[3];
    const float* W1          = (const float*)d_in[4];
    const float* b1          = (const float*)d_in[5];
    const float* W2          = (const float*)d_in[6];
    const float* b2          = (const float*)d_in[7];
    const float* iobs        = (const float*)d_in[8];
    const float* sigiobs     = (const float*)d_in[9];
    const int*   image_id    = (const int*)d_in[10];
    const int*   miller_id   = (const int*)d_in[11];
    float* out = (float*)d_out;

    char* ws = (char*)d_ws;
    float* img_sum = (float*)ws;                 // 8192
    float* img_cnt = img_sum + N_IMAGES;         // 8192
    float* kl_sum  = img_cnt + N_IMAGES;         // 1
    const size_t z_off = 65664;
    bool has_z = (ws_size >= z_off + (size_t)N_RAC * MC * sizeof(float));
    float* zT = has_z ? (float*)(ws + z_off) : nullptr;

    hipMemsetAsync(d_ws, 0, (2 * N_IMAGES + 1) * sizeof(float), stream);

    k_z_kl<<<(N_RAC / 4 + 255) / 256, 256, 0, stream>>>(q_loc, q_log_scale, eps, zT, kl_sum);

    if (has_z) {
        k_main<true><<<(N_REFLNS / 4 + 255) / 256, 256, 0, stream>>>(
            metadata, W1, b1, W2, b2, iobs, sigiobs, image_id, miller_id,
            zT, q_loc, q_log_scale, eps, out, img_sum, img_cnt);
    } else {
        k_main<false><<<(N_REFLNS / 4 + 255) / 256, 256, 0, stream>>>(
            metadata, W1, b1, W2, b2, iobs, sigiobs, image_id, miller_id,
            nullptr, q_loc, q_log_scale, eps, out, img_sum, img_cnt);
    }

    k_final<<<1, 256, 0, stream>>>(img_sum, img_cnt, kl_sum, out);
}